// Round 15
// baseline (596.660 us; speedup 1.0000x reference)
//
#include <hip/hip_runtime.h>

#define B_SZ 2048
#define T_SZ 2048

using f32x16 = float __attribute__((ext_vector_type(16)));
using f32x2  = float __attribute__((ext_vector_type(2)));

// DPP move: result[lane] = src[perm(lane)] (quad_perm / row_ror patterns)
template<int CTRL>
__device__ __forceinline__ float dppf(float v) {
  int r = __builtin_amdgcn_update_dpp(0, __builtin_bit_cast(int, v), CTRL, 0xf, 0xf, true);
  return __builtin_bit_cast(float, r);
}

__device__ __forceinline__ f32x2 pkfma(f32x2 a, f32x2 b, f32x2 c) {
  return __builtin_elementwise_fma(a, b, c);
}

#define SSTR 264                  // stage step stride in dwords
#define SBUF (8 * SSTR)           // one window buffer (8 steps)

// R13 skeleton x TWO independent row-sets per wave, hand-interleaved so the
// scheduler can fill set-A's dependency stalls with set-B's instructions.
// Per set: 4 rows (16-lane group = row; lane owns units sl,sl+16,sl+32,sl+48),
// sliced state x[k] per lane, C-2R folded tanh tail, single role-tree +
// parallel-ror reduce, quad broadcast. Outputs staged to LDS, window-flushed
// as coalesced wide stores (store-WAR off the chain; R13-proven).
__global__ __launch_bounds__(256, 1) void sss_kernel(
    const float* __restrict__ x0p, const float* __restrict__ up,
    const float* __restrict__ tfp, const float* __restrict__ thp,
    const float* __restrict__ tup, const float* __restrict__ typ,
    const float* __restrict__ W1p, const float* __restrict__ b1p,
    const float* __restrict__ W2p, const float* __restrict__ Whp,
    float* __restrict__ outp)
{
  __shared__ float stageF[4 * SBUF];   // [window parity][set]

  const int tid  = threadIdx.x;
  const int lane = tid & 63;
  const int wv   = __builtin_amdgcn_readfirstlane((int)(tid >> 6));
  const int grp  = lane >> 4;              // 16-lane group = row within set
  const int sl   = lane & 15;
  const int k    = lane & 3;               // output channel
  const int b0   = blockIdx.x * 32 + wv * 8;   // 8 rows per wave (2 sets x 4)
  const int bA   = b0 + grp;
  const int bB   = b0 + 4 + grp;

  // ---- prologue (weights SHARED between sets) ----
  // fold K = 2*log2(e): tanh(a) = 1 - 2*rcp(exp2(K*a)+1)
  const float K = 2.8853900817779268f;
  f32x2 w1_01[6], w1_23[6];
#pragma unroll
  for (int r = 0; r < 6; ++r) {
    w1_01[r] = f32x2{W1p[r * 64 + sl]      * K, W1p[r * 64 + sl + 16] * K};
    w1_23[r] = f32x2{W1p[r * 64 + sl + 32] * K, W1p[r * 64 + sl + 48] * K};
  }
  float ccs[4];
#pragma unroll
  for (int i = 0; i < 4; ++i) {
    const int u = sl + 16 * i;
    float t = b1p[u];
#pragma unroll
    for (int q = 0; q < 5; ++q) t = fmaf(tfp[q], W1p[(6 + q) * 64 + u], t);
    ccs[i] = t * K;
  }
  const f32x2 cc01 = f32x2{ccs[0], ccs[1]};
  const f32x2 cc23 = f32x2{ccs[2], ccs[3]};

  const float scale = tup[0] / typ[0];
  // role mapping (R6/R8-proven): wAB[i]={col[k],col[k^1]}, wCD[i]={col[k^2],col[k^3]}
  f32x2 wAB[4], wCD[4];
#pragma unroll
  for (int i = 0; i < 4; ++i) {
    const float4 w2r = ((const float4*)W2p)[sl + 16 * i];
    float col[4] = {w2r.x * scale, w2r.y * scale, w2r.z * scale, w2r.w * scale};
    wAB[i] = f32x2{col[k], col[k ^ 1]};
    wCD[i] = f32x2{col[k ^ 2], col[k ^ 3]};
  }

  // Ck = channel-(k) sum of scaled W2 over all 64 units: role path with r==1
  {
  }
  const f32x2 oAB = (wAB[0] + wAB[1]) + (wAB[2] + wAB[3]);
  const f32x2 oCD = (wCD[0] + wCD[1]) + (wCD[2] + wCD[3]);
  float Cq = (oAB[0] + dppf<0xB1>(oAB[1])) + (dppf<0x4E>(oCD[0]) + dppf<0x1B>(oCD[1]));
  const float Ck = (Cq + dppf<0x124>(Cq)) + (dppf<0x128>(Cq) + dppf<0x12C>(Cq));

  const float whl = Whp[k];
  const float th  = thp[0];
  const float lo = (k == 3) ? -__builtin_inff() : 0.0f;
  const float hi = (k == 3) ?  __builtin_inff() : 10.0f;

  // per-set sliced state + broadcast + y0 (UNCLAMPED, matches reference)
  float xlaneA = x0p[bA * 4 + k];
  float x0vA = dppf<0x00>(xlaneA), x1vA = dppf<0x55>(xlaneA);
  float x2vA = dppf<0xAA>(xlaneA), x3vA = dppf<0xFF>(xlaneA);
  float xCA = xlaneA + Ck;
  float pA0 = xlaneA * whl; pA0 += dppf<0xB1>(pA0); pA0 += dppf<0x4E>(pA0);
  float yvA = pA0 + th;

  float xlaneB = x0p[bB * 4 + k];
  float x0vB = dppf<0x00>(xlaneB), x1vB = dppf<0x55>(xlaneB);
  float x2vB = dppf<0xAA>(xlaneB), x3vB = dppf<0xFF>(xlaneB);
  float xCB = xlaneB + Ck;
  float pB0 = xlaneB * whl; pB0 += dppf<0xB1>(pB0); pB0 += dppf<0x4E>(pB0);
  float yvB = pB0 + th;

  const bool is4 = (sl == 4);

  // ---- staging / flush address setup (R13-proven, per set) ----
  const int m   = sl;
  const int xr  = lane >> 4;
  const int t0  = m >> 1;
  const int k0  = (2 * m) & 3;
  const int rdoff = t0 * SSTR + wv * 64 + 16 * xr + k0;       // dwords
  const int yoff  = (lane & 7) * SSTR + wv * 64 + 16 * (lane >> 3) + 4;
  float2* gxpA = (float2*)outp + (size_t)(b0 + (lane >> 4)) * (T_SZ * 2) + (lane & 15);
  float*  gypA = outp + (size_t)B_SZ * T_SZ * 4 + (size_t)(b0 + (lane >> 3)) * T_SZ + (lane & 7);
  float2* gxpB = (float2*)outp + (size_t)(b0 + 4 + (lane >> 4)) * (T_SZ * 2) + (lane & 15);
  float*  gypB = outp + (size_t)B_SZ * T_SZ * 4 + (size_t)(b0 + 4 + (lane >> 3)) * T_SZ + (lane & 7);

  const f32x16* up16A = (const f32x16*)(up + (size_t)bA * (T_SZ * 2)); // 8 steps/chunk
  const f32x16* up16B = (const f32x16*)(up + (size_t)bB * (T_SZ * 2));
  f32x16 uchA = up16A[0];
  f32x16 uchB = up16B[0];
  const int NC = T_SZ / 8;

  for (int c = 0; c < NC; ++c) {
    const int g = (c + 1 < NC) ? c + 1 : NC - 1;
    const f32x16 unxA = up16A[g];
    const f32x16 unxB = up16B[g];
    float* swA = &stageF[((c & 1) * 2 + 0) * SBUF + tid];
    float* swB = &stageF[((c & 1) * 2 + 1) * SBUF + tid];
#pragma unroll
    for (int jj = 0; jj < 8; ++jj) {
      // ---- capture PRE-update carry into LDS (both sets) ----
      const float vdA = is4 ? yvA : xlaneA;
      swA[jj * SSTR] = vdA;
      const float vdB = is4 ? yvB : xlaneB;
      swB[jj * SSTR] = vdB;

      // u-only bases (off-chain)
      const float u0A = uchA[2 * jj], u1A = uchA[2 * jj + 1];
      const float u0B = uchB[2 * jj], u1B = uchB[2 * jj + 1];
      const f32x2 bA01 = pkfma(f32x2{u1A, u1A}, w1_01[5], pkfma(f32x2{u0A, u0A}, w1_01[4], cc01));
      const f32x2 bB01 = pkfma(f32x2{u1B, u1B}, w1_01[5], pkfma(f32x2{u0B, u0B}, w1_01[4], cc01));
      const f32x2 bA23 = pkfma(f32x2{u1A, u1A}, w1_23[5], pkfma(f32x2{u0A, u0A}, w1_23[4], cc23));
      const f32x2 bB23 = pkfma(f32x2{u1B, u1B}, w1_23[5], pkfma(f32x2{u0B, u0B}, w1_23[4], cc23));

      // matvec (interleaved A/B)
      const f32x2 x0sA = f32x2{x0vA, x0vA}, x1sA = f32x2{x1vA, x1vA};
      const f32x2 x2sA = f32x2{x2vA, x2vA}, x3sA = f32x2{x3vA, x3vA};
      const f32x2 x0sB = f32x2{x0vB, x0vB}, x1sB = f32x2{x1vB, x1vB};
      const f32x2 x2sB = f32x2{x2vB, x2vB}, x3sB = f32x2{x3vB, x3vB};
      const f32x2 mA01A = pkfma(x1sA, w1_01[1], x0sA * w1_01[0]);
      const f32x2 mA01B = pkfma(x1sB, w1_01[1], x0sB * w1_01[0]);
      const f32x2 mB01A = pkfma(x3sA, w1_01[3], x2sA * w1_01[2]);
      const f32x2 mB01B = pkfma(x3sB, w1_01[3], x2sB * w1_01[2]);
      const f32x2 aA01 = (mA01A + mB01A) + bA01;
      const f32x2 aB01 = (mA01B + mB01B) + bB01;
      const f32x2 mA23A = pkfma(x1sA, w1_23[1], x0sA * w1_23[0]);
      const f32x2 mA23B = pkfma(x1sB, w1_23[1], x0sB * w1_23[0]);
      const f32x2 mB23A = pkfma(x3sA, w1_23[3], x2sA * w1_23[2]);
      const f32x2 mB23B = pkfma(x3sB, w1_23[3], x2sB * w1_23[2]);
      const f32x2 aA23 = (mA23A + mB23A) + bA23;
      const f32x2 aB23 = (mA23B + mB23B) + bB23;

      // r = rcp(exp2(acc)+1), 4 units per set (interleaved)
      float rA[4], rB[4];
      {
        const float avA[4] = {aA01[0], aA01[1], aA23[0], aA23[1]};
        const float avB[4] = {aB01[0], aB01[1], aB23[0], aB23[1]};
#pragma unroll
        for (int i = 0; i < 4; ++i) {
          const float eA = __builtin_amdgcn_exp2f(avA[i]);
          const float eB = __builtin_amdgcn_exp2f(avB[i]);
          rA[i] = __builtin_amdgcn_rcpf(eA + 1.0f);
          rB[i] = __builtin_amdgcn_rcpf(eB + 1.0f);
        }
      }

      // fold on r (2-level tree, packed roles)
      const f32x2 qABA = pkfma(f32x2{rA[1], rA[1]}, wAB[1], f32x2{rA[0], rA[0]} * wAB[0])
                       + pkfma(f32x2{rA[3], rA[3]}, wAB[3], f32x2{rA[2], rA[2]} * wAB[2]);
      const f32x2 qABB = pkfma(f32x2{rB[1], rB[1]}, wAB[1], f32x2{rB[0], rB[0]} * wAB[0])
                       + pkfma(f32x2{rB[3], rB[3]}, wAB[3], f32x2{rB[2], rB[2]} * wAB[2]);
      const f32x2 qCDA = pkfma(f32x2{rA[1], rA[1]}, wCD[1], f32x2{rA[0], rA[0]} * wCD[0])
                       + pkfma(f32x2{rA[3], rA[3]}, wCD[3], f32x2{rA[2], rA[2]} * wCD[2]);
      const f32x2 qCDB = pkfma(f32x2{rB[1], rB[1]}, wCD[1], f32x2{rB[0], rB[0]} * wCD[0])
                       + pkfma(f32x2{rB[3], rB[3]}, wCD[3], f32x2{rB[2], rB[2]} * wCD[2]);

      // role quad-tree (3 parallel dpps + 2 adds), then parallel-ror all-phase sum
      const float vA = (qABA[0] + dppf<0xB1>(qABA[1]))
                     + (dppf<0x4E>(qCDA[0]) + dppf<0x1B>(qCDA[1]));
      const float vB = (qABB[0] + dppf<0xB1>(qABB[1]))
                     + (dppf<0x4E>(qCDB[0]) + dppf<0x1B>(qCDB[1]));
      const float VA = (vA + dppf<0x124>(vA)) + (dppf<0x128>(vA) + dppf<0x12C>(vA));
      const float VB = (vB + dppf<0x124>(vB)) + (dppf<0x128>(vB) + dppf<0x12C>(vB));

      // w = x + C - 2V (pre-clip x_raw[k])
      const float wA = fmaf(-2.0f, VA, xCA);
      const float wB = fmaf(-2.0f, VB, xCB);

      // y from PRE-clip state (off-chain quad reduce)
      float pA = wA * whl; pA += dppf<0xB1>(pA); pA += dppf<0x4E>(pA);
      yvA = __builtin_amdgcn_fmed3f(pA + th, 0.0f, 10.0f);
      float pB = wB * whl; pB += dppf<0xB1>(pB); pB += dppf<0x4E>(pB);
      yvB = __builtin_amdgcn_fmed3f(pB + th, 0.0f, 10.0f);

      // clip + fold-carrier + broadcast
      xlaneA = __builtin_amdgcn_fmed3f(wA, lo, hi);
      xlaneB = __builtin_amdgcn_fmed3f(wB, lo, hi);
      xCA = xlaneA + Ck;
      xCB = xlaneB + Ck;
      x0vA = dppf<0x00>(xlaneA); x0vB = dppf<0x00>(xlaneB);
      x1vA = dppf<0x55>(xlaneA); x1vB = dppf<0x55>(xlaneB);
      x2vA = dppf<0xAA>(xlaneA); x2vB = dppf<0xAA>(xlaneB);
      x3vA = dppf<0xFF>(xlaneA); x3vB = dppf<0xFF>(xlaneB);
    }
    // ---- window flush (R13-proven), both sets ----
    {
      const int bbA = ((c & 1) * 2 + 0) * SBUF;
      const int bbB = ((c & 1) * 2 + 1) * SBUF;
      const float2 xvA = *(const float2*)&stageF[bbA + rdoff];
      const float2 xvB = *(const float2*)&stageF[bbB + rdoff];
      *gxpA = xvA;
      *gxpB = xvB;
      if (lane < 32) {
        const float yyA = stageF[bbA + yoff];
        const float yyB = stageF[bbB + yoff];
        *gypA = yyA;
        *gypB = yyB;
      }
      gxpA += 16; gxpB += 16;
      gypA += 8;  gypB += 8;
    }
    uchA = unxA;
    uchB = unxB;
  }
}

extern "C" void kernel_launch(void* const* d_in, const int* in_sizes, int n_in,
                              void* d_out, int out_size, void* d_ws, size_t ws_size,
                              hipStream_t stream) {
  (void)in_sizes; (void)n_in; (void)out_size; (void)d_ws; (void)ws_size;
  sss_kernel<<<dim3(B_SZ / 32), dim3(256), 0, stream>>>(
      (const float*)d_in[0], (const float*)d_in[1], (const float*)d_in[2],
      (const float*)d_in[3], (const float*)d_in[4], (const float*)d_in[5],
      (const float*)d_in[6], (const float*)d_in[7], (const float*)d_in[8],
      (const float*)d_in[9], (float*)d_out);
}

// Round 16
// 358.807 us; speedup vs baseline: 1.6629x; 1.6629x over previous
//
#include <hip/hip_runtime.h>

#define B_SZ 2048
#define T_SZ 2048

using f32x16 = float __attribute__((ext_vector_type(16)));
using f32x2  = float __attribute__((ext_vector_type(2)));

// DPP move: result[lane] = src[perm(lane)] (quad_perm / row_ror; all HW-proven)
template<int CTRL>
__device__ __forceinline__ float dppf(float v) {
  int r = __builtin_amdgcn_update_dpp(0, __builtin_bit_cast(int, v), CTRL, 0xf, 0xf, true);
  return __builtin_bit_cast(float, r);
}

__device__ __forceinline__ f32x2 pkfma(f32x2 a, f32x2 b, f32x2 c) {
  return __builtin_elementwise_fma(a, b, c);
}

#define SSTR 268                  // stage step stride in dwords (%4==0 for b128)
#define SBUF (8 * SSTR)           // one window buffer (8 steps)

// R13 skeleton (4 rows/wave, 16-lane group = row, lane owns units
// sl,sl+16,sl+32,sl+48, sliced state x[k], LDS-staged outputs) with three
// chain trims: C-2R folded tanh tail (fold on r, w = fma(-2,V,xC)),
// parallel-ror reduce (ror4/8/12 in ONE dpp level), tree-shaped fold.
// Flush: half-wave ds_read_b128 -> float4 store (x), half-wave dword (y).
__global__ __launch_bounds__(256, 1) void sss_kernel(
    const float* __restrict__ x0p, const float* __restrict__ up,
    const float* __restrict__ tfp, const float* __restrict__ thp,
    const float* __restrict__ tup, const float* __restrict__ typ,
    const float* __restrict__ W1p, const float* __restrict__ b1p,
    const float* __restrict__ W2p, const float* __restrict__ Whp,
    float* __restrict__ outp)
{
  __shared__ float stageF[2 * SBUF];   // double-buffered by window parity

  const int tid  = threadIdx.x;
  const int lane = tid & 63;
  const int wv   = __builtin_amdgcn_readfirstlane((int)(tid >> 6));
  const int grp  = lane >> 4;              // 16-lane group = row within wave
  const int sl   = lane & 15;              // sub-lane within group
  const int k    = lane & 3;               // output channel
  const int b0   = blockIdx.x * 16 + wv * 4;
  const int b    = b0 + grp;               // this lane's batch row

  // ---- prologue ----
  // fold K = 2*log2(e): tanh(a) = 1 - 2*rcp(exp2(K*a)+1)
  const float K = 2.8853900817779268f;
  f32x2 w1_01[6], w1_23[6];
#pragma unroll
  for (int r = 0; r < 6; ++r) {
    w1_01[r] = f32x2{W1p[r * 64 + sl]      * K, W1p[r * 64 + sl + 16] * K};
    w1_23[r] = f32x2{W1p[r * 64 + sl + 32] * K, W1p[r * 64 + sl + 48] * K};
  }
  float ccs[4];
#pragma unroll
  for (int i = 0; i < 4; ++i) {
    const int u = sl + 16 * i;
    float t = b1p[u];
#pragma unroll
    for (int q = 0; q < 5; ++q) t = fmaf(tfp[q], W1p[(6 + q) * 64 + u], t);
    ccs[i] = t * K;
  }
  const f32x2 cc01 = f32x2{ccs[0], ccs[1]};
  const f32x2 cc23 = f32x2{ccs[2], ccs[3]};

  const float scale = tup[0] / typ[0];
  // role mapping (R8-proven): wAB[i]={col[k],col[k^1]}, wCD[i]={col[k^2],col[k^3]}
  f32x2 wAB[4], wCD[4];
#pragma unroll
  for (int i = 0; i < 4; ++i) {
    const float4 w2r = ((const float4*)W2p)[sl + 16 * i];
    float col[4] = {w2r.x * scale, w2r.y * scale, w2r.z * scale, w2r.w * scale};
    wAB[i] = f32x2{col[k], col[k ^ 1]};
    wCD[i] = f32x2{col[k ^ 2], col[k ^ 3]};
  }

  // Ck = channel-k sum of scaled W2 over all 64 units (R15-proven prologue)
  const f32x2 oAB = (wAB[0] + wAB[1]) + (wAB[2] + wAB[3]);
  const f32x2 oCD = (wCD[0] + wCD[1]) + (wCD[2] + wCD[3]);
  float Cq = (oAB[0] + dppf<0xB1>(oAB[1])) + (dppf<0x4E>(oCD[0]) + dppf<0x1B>(oCD[1]));
  const float Ck = (Cq + dppf<0x124>(Cq)) + (dppf<0x128>(Cq) + dppf<0x12C>(Cq));

  const float whl = Whp[k];            // Wh[k][0]
  const float th  = thp[0];
  const float lo = (k == 3) ? -__builtin_inff() : 0.0f;
  const float hi = (k == 3) ?  __builtin_inff() : 10.0f;

  // per-lane state: xlane = x[k] (replicated per quad) + broadcast + carrier
  float xlane = x0p[b * 4 + k];
  float x0v = dppf<0x00>(xlane);
  float x1v = dppf<0x55>(xlane);
  float x2v = dppf<0xAA>(xlane);
  float x3v = dppf<0xFF>(xlane);
  float xC  = xlane + Ck;

  // y0 = h(x_0), UNCLAMPED (matches reference)
  float p0 = xlane * whl;
  p0 += dppf<0xB1>(p0);
  p0 += dppf<0x4E>(p0);
  float yv = p0 + th;

  const bool doSt = (sl < 5);
  const bool is4  = (sl == 4);

  // ---- flush setup: lanes 0-31 -> x (b128 + float4), lanes 32-63 -> y ----
  const int fr  = (lane & 31) >> 3;        // row 0..3
  const int fs  = lane & 7;                // step 0..7
  const bool isX = lane < 32;
  const int rdX = fs * SSTR + wv * 64 + fr * 16;   // dword offset (16B aligned)
  const int rdY = rdX + 4;
  float4* gxp = (float4*)outp + (size_t)(b0 + fr) * T_SZ + fs;
  float*  gyp = outp + (size_t)B_SZ * T_SZ * 4 + (size_t)(b0 + fr) * T_SZ + fs;

  const f32x16* up16 = (const f32x16*)(up + (size_t)b * (T_SZ * 2)); // 8 steps/chunk
  f32x16 uch = up16[0];
  const int NC = T_SZ / 8;

  for (int c = 0; c < NC; ++c) {
    const int g = (c + 1 < NC) ? c + 1 : NC - 1;   // prefetch next chunk
    const f32x16 unx = up16[g];
    float* sw = &stageF[(c & 1) * SBUF + tid];     // this window's write base
#pragma unroll
    for (int jj = 0; jj < 8; ++jj) {
      // ---- capture PRE-update carry (x_step, y_step) into LDS ----
      const float vdata = is4 ? yv : xlane;
      if (doSt) sw[jj * SSTR] = vdata;             // ds_write_b32, fire-forget

      const float u0 = uch[2 * jj];
      const float u1 = uch[2 * jj + 1];
      const f32x2 u0p = f32x2{u0, u0};
      const f32x2 u1p = f32x2{u1, u1};

      // u-only bases (off-chain)
      const f32x2 b01 = pkfma(u1p, w1_01[5], pkfma(u0p, w1_01[4], cc01));
      const f32x2 b23 = pkfma(u1p, w1_23[5], pkfma(u0p, w1_23[4], cc23));

      // x-part matvec (on-chain, depth ~4 from broadcast)
      const f32x2 x0s = f32x2{x0v, x0v};
      const f32x2 x1s = f32x2{x1v, x1v};
      const f32x2 x2s = f32x2{x2v, x2v};
      const f32x2 x3s = f32x2{x3v, x3v};
      const f32x2 mA01 = pkfma(x1s, w1_01[1], x0s * w1_01[0]);
      const f32x2 mB01 = pkfma(x3s, w1_01[3], x2s * w1_01[2]);
      const f32x2 a01  = (b01 + mA01) + mB01;
      const f32x2 mA23 = pkfma(x1s, w1_23[1], x0s * w1_23[0]);
      const f32x2 mB23 = pkfma(x3s, w1_23[3], x2s * w1_23[2]);
      const f32x2 a23  = (b23 + mA23) + mB23;

      // r = rcp(exp2(acc)+1), 4 units (C-2R: no h-fma)
      float r_[4];
      {
        const float av[4] = {a01[0], a01[1], a23[0], a23[1]};
#pragma unroll
        for (int i = 0; i < 4; ++i) {
          const float e  = __builtin_amdgcn_exp2f(av[i]);
          r_[i] = __builtin_amdgcn_rcpf(e + 1.0f);
        }
      }
      const f32x2 r0s = f32x2{r_[0], r_[0]};
      const f32x2 r1s = f32x2{r_[1], r_[1]};
      const f32x2 r2s = f32x2{r_[2], r_[2]};
      const f32x2 r3s = f32x2{r_[3], r_[3]};

      // fold on r, TREE shape (depth 3)
      const f32x2 qAB = pkfma(r1s, wAB[1], r0s * wAB[0])
                      + pkfma(r3s, wAB[3], r2s * wAB[2]);
      const f32x2 qCD = pkfma(r1s, wCD[1], r0s * wCD[0])
                      + pkfma(r3s, wCD[3], r2s * wCD[2]);

      // quad tree: 3 parallel dpps (xor1/xor2/xor3) -> quad channel-k sum
      const float v = (qAB[0] + dppf<0xB1>(qAB[1]))
                    + (dppf<0x4E>(qCD[0]) + dppf<0x1B>(qCD[1]));
      // parallel-ror: ONE dpp level (ror4/8/12) -> full 64-unit channel-k sum
      const float V = (v + dppf<0x124>(v)) + (dppf<0x128>(v) + dppf<0x12C>(v));

      // w = x + Ck - 2V (pre-clip x_raw[k]); xC precomputed off-chain
      const float w = fmaf(-2.0f, V, xC);

      // y from PRE-clip state (off-chain quad reduce)
      float p = w * whl;
      p += dppf<0xB1>(p);
      p += dppf<0x4E>(p);
      yv = __builtin_amdgcn_fmed3f(p + th, 0.0f, 10.0f);

      // clip + carrier + broadcast
      xlane = __builtin_amdgcn_fmed3f(w, lo, hi);   // channel 3 unbounded
      xC = xlane + Ck;                              // off-chain (ready early)
      x0v = dppf<0x00>(xlane);
      x1v = dppf<0x55>(xlane);
      x2v = dppf<0xAA>(xlane);
      x3v = dppf<0xFF>(xlane);
    }
    // ---- window flush: half-wave x (b128 -> float4), half-wave y ----
    {
      const int bb = (c & 1) * SBUF;
      if (isX) {
        const float4 xv = *(const float4*)&stageF[bb + rdX];  // ds_read_b128
        *gxp = xv;                                            // dwordx4, coalesced
        gxp += 8;
      } else {
        const float yy = stageF[bb + rdY];
        *gyp = yy;
        gyp += 8;
      }
    }
    uch = unx;
  }
}

extern "C" void kernel_launch(void* const* d_in, const int* in_sizes, int n_in,
                              void* d_out, int out_size, void* d_ws, size_t ws_size,
                              hipStream_t stream) {
  (void)in_sizes; (void)n_in; (void)out_size; (void)d_ws; (void)ws_size;
  sss_kernel<<<dim3(B_SZ / 16), dim3(256), 0, stream>>>(
      (const float*)d_in[0], (const float*)d_in[1], (const float*)d_in[2],
      (const float*)d_in[3], (const float*)d_in[4], (const float*)d_in[5],
      (const float*)d_in[6], (const float*)d_in[7], (const float*)d_in[8],
      (const float*)d_in[9], (float*)d_out);
}